// Round 3
// baseline (277.062 us; speedup 1.0000x reference)
//
#include <hip/hip_runtime.h>

typedef unsigned short u16;
using bf16x8 = __attribute__((ext_vector_type(8))) __bf16;
using f32x4  = __attribute__((ext_vector_type(4))) float;
using u16x8  = __attribute__((ext_vector_type(8))) unsigned short;
using u16x4  = __attribute__((ext_vector_type(4))) unsigned short;

#define SEQ   2048
#define HID   1024
#define NHEAD 16
#define HD    64
#define BATCH 2
#define NTOK  4096   // BATCH*SEQ

__device__ __forceinline__ u16 f2bf(float f) {
  unsigned u = __builtin_bit_cast(unsigned, f);
  u += 0x7fffu + ((u >> 16) & 1u);
  return (u16)(u >> 16);
}

__device__ __forceinline__ void gld_lds16(const void* g, void* l) {
  __builtin_amdgcn_global_load_lds(
      (__attribute__((address_space(1))) void*)(__UINTPTR_TYPE__)g,
      (__attribute__((address_space(3))) void*)l, 16, 0, 0);
}

// ---------------- fp32 -> bf16 convert ----------------
__global__ __launch_bounds__(256) void cvt_kernel(const float* __restrict__ in,
                                                  u16* __restrict__ out) {
  int i = (blockIdx.x * 256 + threadIdx.x) * 4;
  float4 v = *reinterpret_cast<const float4*>(in + i);
  u16x4 o = { f2bf(v.x), f2bf(v.y), f2bf(v.z), f2bf(v.w) };
  *reinterpret_cast<u16x4*>(out + i) = o;
}

// ---------------- GEMM: C[M,N] = A[M,K] * B[N,K]^T ----------------
// 128x128 tile, BK=64, 4 waves (2x2), each wave 64x64 (4x4 frags of 16x16x32)
template<bool BF16OUT>
__global__ __launch_bounds__(256) void gemm_bt(const u16* __restrict__ A,
                                               const u16* __restrict__ B,
                                               void* __restrict__ Cv,
                                               int M, int N, int K) {
  __shared__ u16 At[128 * 64];
  __shared__ u16 Bt[128 * 64];
  const int tid  = threadIdx.x;
  const int wave = tid >> 6;
  const int lane = tid & 63;
  const int g    = lane >> 4;
  const int r16  = lane & 15;
  const int wr   = wave >> 1;
  const int wc   = wave & 1;
  const int bm   = blockIdx.y;
  const int bn   = blockIdx.x;

  const u16* Ab = A + (size_t)bm * 128 * K;
  const u16* Bb = B + (size_t)bn * 128 * K;
  const int srow = lane >> 3;        // 0..7 within an 8-row segment
  const int scol = (lane & 7) * 8;   // element offset (16B chunks)

  f32x4 acc[4][4] = {};

  for (int kt = 0; kt < K; kt += 64) {
#pragma unroll
    for (int c = 0; c < 4; ++c) {
      int seg = wave * 4 + c;        // 16 segments of 1KB per tile
      gld_lds16(Ab + (size_t)(seg * 8 + srow) * K + kt + scol, &At[seg * 512]);
      gld_lds16(Bb + (size_t)(seg * 8 + srow) * K + kt + scol, &Bt[seg * 512]);
    }
    __syncthreads();
#pragma unroll
    for (int ko = 0; ko < 64; ko += 32) {
      bf16x8 af[4], bfr[4];
#pragma unroll
      for (int mi = 0; mi < 4; ++mi)
        af[mi] = *reinterpret_cast<const bf16x8*>(&At[(wr * 64 + mi * 16 + r16) * 64 + ko + g * 8]);
#pragma unroll
      for (int ni = 0; ni < 4; ++ni)
        bfr[ni] = *reinterpret_cast<const bf16x8*>(&Bt[(wc * 64 + ni * 16 + r16) * 64 + ko + g * 8]);
#pragma unroll
      for (int mi = 0; mi < 4; ++mi)
#pragma unroll
        for (int ni = 0; ni < 4; ++ni)
          acc[mi][ni] = __builtin_amdgcn_mfma_f32_16x16x32_bf16(af[mi], bfr[ni], acc[mi][ni], 0, 0, 0);
    }
    __syncthreads();
  }

#pragma unroll
  for (int mi = 0; mi < 4; ++mi)
#pragma unroll
    for (int ni = 0; ni < 4; ++ni) {
      int row0 = bm * 128 + wr * 64 + mi * 16 + g * 4;
      int col  = bn * 128 + wc * 64 + ni * 16 + r16;
#pragma unroll
      for (int r = 0; r < 4; ++r) {
        float v = acc[mi][ni][r];
        if (BF16OUT) ((u16*)Cv)[(size_t)(row0 + r) * N + col] = f2bf(v);
        else         ((float*)Cv)[(size_t)(row0 + r) * N + col] = v;
      }
    }
}

// ---------------- flash attention ----------------
// grid: (S/128, BATCH*NHEAD); 4 waves, each wave 32 q-rows; K-tile = 64 keys
__global__ __launch_bounds__(256) void attn_kernel(const u16* __restrict__ qkv,
                                                   const float* __restrict__ mask,
                                                   u16* __restrict__ AO) {
  __shared__ u16 Kt[64 * 64];      // [key][d]
  __shared__ u16 Vt[64 * 64];      // [d][key] (transposed)
  __shared__ u16 Pl[4][32 * 64];   // per-wave P

  const int tid  = threadIdx.x;
  const int w    = tid >> 6;
  const int lane = tid & 63;
  const int g    = lane >> 4;
  const int r16  = lane & 15;
  const int qt   = blockIdx.x;          // 0..15
  const int bh   = blockIdx.y;          // 0..31
  const int b    = bh >> 4;
  const int h    = bh & 15;

  const size_t tokbase = (size_t)b * SEQ;

  // Q fragments direct from global (read once)
  bf16x8 aq[2][2];
#pragma unroll
  for (int mi = 0; mi < 2; ++mi)
#pragma unroll
    for (int ko = 0; ko < 2; ++ko) {
      int qrow = qt * 128 + w * 32 + mi * 16 + r16;
      const u16* p = qkv + ((tokbase + qrow) * 3 + 0) * HID + h * HD + ko * 32 + g * 8;
      aq[mi][ko] = *reinterpret_cast<const bf16x8*>(p);
    }

  f32x4 o[2][4] = {};
  float mrow[2][4], lrow[2][4];
#pragma unroll
  for (int mi = 0; mi < 2; ++mi)
#pragma unroll
    for (int r = 0; r < 4; ++r) { mrow[mi][r] = -3.0e38f; lrow[mi][r] = 0.f; }

  const int srowK = lane >> 3;
  const int scolK = (lane & 7) * 8;
  const int vkey  = tid >> 2;           // 0..63
  const int vd0   = (tid & 3) * 16;

#pragma unroll 1
  for (int kb = 0; kb < SEQ; kb += 64) {
    __syncthreads();   // previous iteration's reads of Kt/Vt/Pl done
    // stage K tile [64][64]
#pragma unroll
    for (int c = 0; c < 2; ++c) {
      int seg = w * 2 + c;
      gld_lds16(qkv + ((tokbase + kb + seg * 8 + srowK) * 3 + 1) * HID + h * HD + scolK,
                &Kt[seg * 512]);
    }
    // stage V transposed: coalesced global read, scalar LDS writes
    {
      const u16* vp = qkv + ((tokbase + kb + vkey) * 3 + 2) * HID + h * HD + vd0;
      u16x8 v0 = *reinterpret_cast<const u16x8*>(vp);
      u16x8 v1 = *reinterpret_cast<const u16x8*>(vp + 8);
#pragma unroll
      for (int j = 0; j < 8; ++j) {
        Vt[(vd0 + j) * 64 + vkey]     = v0[j];
        Vt[(vd0 + 8 + j) * 64 + vkey] = v1[j];
      }
    }
    __syncthreads();

    // S = Q K^T  (per wave: 32q x 64k)
    f32x4 sf[2][4] = {};
#pragma unroll
    for (int ko = 0; ko < 2; ++ko) {
      bf16x8 bk[4];
#pragma unroll
      for (int ni = 0; ni < 4; ++ni)
        bk[ni] = *reinterpret_cast<const bf16x8*>(&Kt[(ni * 16 + r16) * 64 + ko * 32 + g * 8]);
#pragma unroll
      for (int mi = 0; mi < 2; ++mi)
#pragma unroll
        for (int ni = 0; ni < 4; ++ni)
          sf[mi][ni] = __builtin_amdgcn_mfma_f32_16x16x32_bf16(aq[mi][ko], bk[ni], sf[mi][ni], 0, 0, 0);
    }

    // scale + mask + online softmax (rows live at g*4+r, cols at r16)
#pragma unroll
    for (int mi = 0; mi < 2; ++mi) {
#pragma unroll
      for (int r = 0; r < 4; ++r) {
        int q = qt * 128 + w * 32 + mi * 16 + g * 4 + r;
        const float* mrowp = mask + ((size_t)b * SEQ + q) * SEQ + kb;
        float mx = -3.0e38f;
#pragma unroll
        for (int ni = 0; ni < 4; ++ni) {
          float sv = sf[mi][ni][r] * 0.125f + mrowp[ni * 16 + r16];
          sf[mi][ni][r] = sv;
          mx = fmaxf(mx, sv);
        }
        mx = fmaxf(mx, __shfl_xor(mx, 1));
        mx = fmaxf(mx, __shfl_xor(mx, 2));
        mx = fmaxf(mx, __shfl_xor(mx, 4));
        mx = fmaxf(mx, __shfl_xor(mx, 8));
        float mnew  = fmaxf(mrow[mi][r], mx);
        float alpha = __expf(mrow[mi][r] - mnew);
        mrow[mi][r] = mnew;
        float s = 0.f;
#pragma unroll
        for (int ni = 0; ni < 4; ++ni) {
          float p = __expf(sf[mi][ni][r] - mnew);
          sf[mi][ni][r] = p;
          s += p;
        }
        s += __shfl_xor(s, 1); s += __shfl_xor(s, 2);
        s += __shfl_xor(s, 4); s += __shfl_xor(s, 8);
        lrow[mi][r] = lrow[mi][r] * alpha + s;
#pragma unroll
        for (int di = 0; di < 4; ++di) o[mi][di][r] *= alpha;
#pragma unroll
        for (int ni = 0; ni < 4; ++ni)
          Pl[w][(mi * 16 + g * 4 + r) * 64 + ni * 16 + r16] = f2bf(sf[mi][ni][r]);
      }
    }
    __syncthreads();   // P visible (cross-lane), lgkm drained

    // O += P V   (contraction over 64 keys)
#pragma unroll
    for (int kk = 0; kk < 2; ++kk) {
      bf16x8 pa[2], bv[4];
#pragma unroll
      for (int mi = 0; mi < 2; ++mi)
        pa[mi] = *reinterpret_cast<const bf16x8*>(&Pl[w][(mi * 16 + r16) * 64 + kk * 32 + g * 8]);
#pragma unroll
      for (int di = 0; di < 4; ++di)
        bv[di] = *reinterpret_cast<const bf16x8*>(&Vt[(di * 16 + r16) * 64 + kk * 32 + g * 8]);
#pragma unroll
      for (int mi = 0; mi < 2; ++mi)
#pragma unroll
        for (int di = 0; di < 4; ++di)
          o[mi][di] = __builtin_amdgcn_mfma_f32_16x16x32_bf16(pa[mi], bv[di], o[mi][di], 0, 0, 0);
    }
  }

  // finalize: divide by l, store bf16 to AO[token, h*64+d]
#pragma unroll
  for (int mi = 0; mi < 2; ++mi)
#pragma unroll
    for (int di = 0; di < 4; ++di)
#pragma unroll
      for (int r = 0; r < 4; ++r) {
        int srow = qt * 128 + w * 32 + mi * 16 + g * 4 + r;
        float val = o[mi][di][r] / lrow[mi][r];
        AO[(tokbase + srow) * HID + h * HD + di * 16 + r16] = f2bf(val);
      }
}

// ---------------- launcher ----------------
extern "C" void kernel_launch(void* const* d_in, const int* in_sizes, int n_in,
                              void* d_out, int out_size, void* d_ws, size_t ws_size,
                              hipStream_t stream) {
  (void)in_sizes; (void)n_in; (void)out_size; (void)ws_size;
  const float* hs   = (const float*)d_in[0];
  const float* mask = (const float*)d_in[1];
  const float* wqkv = (const float*)d_in[2];
  const float* wo   = (const float*)d_in[3];
  float* out = (float*)d_out;

  char* ws   = (char*)d_ws;
  u16* Xb    = (u16*)(ws);                        // 4096x1024  (8 MiB)
  u16* Wqkvb = (u16*)(ws + 8u  * 1024 * 1024);    // 3072x1024  (6 MiB)
  u16* Wob   = (u16*)(ws + 14u * 1024 * 1024);    // 1024x1024  (2 MiB)
  u16* QKVb  = (u16*)(ws + 16u * 1024 * 1024);    // 4096x3072  (24 MiB)
  u16* AOb   = (u16*)(ws + 40u * 1024 * 1024);    // 4096x1024  (8 MiB)

  cvt_kernel<<<4096, 256, 0, stream>>>(hs,   Xb);
  cvt_kernel<<<3072, 256, 0, stream>>>(wqkv, Wqkvb);
  cvt_kernel<<<1024, 256, 0, stream>>>(wo,   Wob);

  gemm_bt<true ><<<dim3(3072 / 128, 4096 / 128), 256, 0, stream>>>(Xb,  Wqkvb, QKVb, NTOK, 3072, HID);
  attn_kernel   <<<dim3(SEQ / 128, BATCH * NHEAD), 256, 0, stream>>>(QKVb, mask, AOb);
  gemm_bt<false><<<dim3(1024 / 128, 4096 / 128), 256, 0, stream>>>(AOb, Wob,  out,  NTOK, 1024, HID);
}

// Round 4
// 212.261 us; speedup vs baseline: 1.3053x; 1.3053x over previous
//
#include <hip/hip_runtime.h>

typedef unsigned short u16;
using bf16x8 = __attribute__((ext_vector_type(8))) __bf16;
using f32x4  = __attribute__((ext_vector_type(4))) float;
using u16x8  = __attribute__((ext_vector_type(8))) unsigned short;
using u16x4  = __attribute__((ext_vector_type(4))) unsigned short;

#define SEQ   2048
#define HID   1024
#define NHEAD 16
#define HD    64
#define BATCH 2
#define NTOK  4096   // BATCH*SEQ

__device__ __forceinline__ u16 f2bf(float f) {
  unsigned u = __builtin_bit_cast(unsigned, f);
  u += 0x7fffu + ((u >> 16) & 1u);
  return (u16)(u >> 16);
}

__device__ __forceinline__ void gld_lds16(const void* g, void* l) {
  __builtin_amdgcn_global_load_lds(
      (__attribute__((address_space(1))) void*)(__UINTPTR_TYPE__)g,
      (__attribute__((address_space(3))) void*)l, 16, 0, 0);
}

// ---------------- fp32 -> bf16 convert ----------------
__global__ __launch_bounds__(256) void cvt_kernel(const float* __restrict__ in,
                                                  u16* __restrict__ out) {
  int i = (blockIdx.x * 256 + threadIdx.x) * 4;
  float4 v = *reinterpret_cast<const float4*>(in + i);
  u16x4 o = { f2bf(v.x), f2bf(v.y), f2bf(v.z), f2bf(v.w) };
  *reinterpret_cast<u16x4*>(out + i) = o;
}

// ---------------- GEMM: C[M,N] = A[M,K] * B[N,K]^T ---------------- (unchanged)
template<bool BF16OUT>
__global__ __launch_bounds__(256) void gemm_bt(const u16* __restrict__ A,
                                               const u16* __restrict__ B,
                                               void* __restrict__ Cv,
                                               int M, int N, int K) {
  __shared__ u16 At[128 * 64];
  __shared__ u16 Bt[128 * 64];
  const int tid  = threadIdx.x;
  const int wave = tid >> 6;
  const int lane = tid & 63;
  const int g    = lane >> 4;
  const int r16  = lane & 15;
  const int wr   = wave >> 1;
  const int wc   = wave & 1;
  const int bm   = blockIdx.y;
  const int bn   = blockIdx.x;

  const u16* Ab = A + (size_t)bm * 128 * K;
  const u16* Bb = B + (size_t)bn * 128 * K;
  const int srow = lane >> 3;
  const int scol = (lane & 7) * 8;

  f32x4 acc[4][4] = {};

  for (int kt = 0; kt < K; kt += 64) {
#pragma unroll
    for (int c = 0; c < 4; ++c) {
      int seg = wave * 4 + c;
      gld_lds16(Ab + (size_t)(seg * 8 + srow) * K + kt + scol, &At[seg * 512]);
      gld_lds16(Bb + (size_t)(seg * 8 + srow) * K + kt + scol, &Bt[seg * 512]);
    }
    __syncthreads();
#pragma unroll
    for (int ko = 0; ko < 64; ko += 32) {
      bf16x8 af[4], bfr[4];
#pragma unroll
      for (int mi = 0; mi < 4; ++mi)
        af[mi] = *reinterpret_cast<const bf16x8*>(&At[(wr * 64 + mi * 16 + r16) * 64 + ko + g * 8]);
#pragma unroll
      for (int ni = 0; ni < 4; ++ni)
        bfr[ni] = *reinterpret_cast<const bf16x8*>(&Bt[(wc * 64 + ni * 16 + r16) * 64 + ko + g * 8]);
#pragma unroll
      for (int mi = 0; mi < 4; ++mi)
#pragma unroll
        for (int ni = 0; ni < 4; ++ni)
          acc[mi][ni] = __builtin_amdgcn_mfma_f32_16x16x32_bf16(af[mi], bfr[ni], acc[mi][ni], 0, 0, 0);
    }
    __syncthreads();
  }

#pragma unroll
  for (int mi = 0; mi < 4; ++mi)
#pragma unroll
    for (int ni = 0; ni < 4; ++ni) {
      int row0 = bm * 128 + wr * 64 + mi * 16 + g * 4;
      int col  = bn * 128 + wc * 64 + ni * 16 + r16;
#pragma unroll
      for (int r = 0; r < 4; ++r) {
        float v = acc[mi][ni][r];
        if (BF16OUT) ((u16*)Cv)[(size_t)(row0 + r) * N + col] = f2bf(v);
        else         ((float*)Cv)[(size_t)(row0 + r) * N + col] = v;
      }
    }
}

// ---------------- flash attention ----------------
// 1024 blocks (1-D, XCD-chunked remap), 4 waves, each wave 16 q-rows; K-tile = 64
// All LDS tiles [row][64 u16] XOR-swizzled on the 16B-chunk index:
//   s(row) = ((row>>4) + (row&7)) & 7 ; chunk' = chunk ^ s(row)
__global__ __launch_bounds__(256, 4) void attn_kernel(const u16* __restrict__ qkv,
                                                      const float* __restrict__ mask,
                                                      u16* __restrict__ AO) {
  __shared__ u16 Kt[64 * 64];      // [key][d]   swizzled
  __shared__ u16 Vt[64 * 64];      // [d][key]   swizzled (transposed)
  __shared__ u16 Pl[4][16 * 64];   // per-wave P swizzled

  const int tid  = threadIdx.x;
  const int w    = tid >> 6;
  const int lane = tid & 63;
  const int g    = lane >> 4;
  const int r16  = lane & 15;

  // XCD-chunked remap: 16 heads of one (b,qt) share an XCD (mask L2 reuse)
  const int n  = blockIdx.x;          // 0..1023
  const int x  = n & 7;
  const int s_ = n >> 3;              // 0..127
  const int h  = s_ & 15;
  const int t  = ((s_ >> 4) << 3) + x; // 0..63
  const int b  = t >> 5;
  const int qt = t & 31;              // 0..31 (64-row q tiles)

  const size_t tokbase = (size_t)b * SEQ;

  // Q fragments direct from global (read once); qrow = qt*64 + w*16 + r16
  bf16x8 aq[2];
  {
    int qrow = qt * 64 + w * 16 + r16;
#pragma unroll
    for (int ko = 0; ko < 2; ++ko)
      aq[ko] = *reinterpret_cast<const bf16x8*>(
          qkv + ((tokbase + qrow) * 3 + 0) * HID + h * HD + ko * 32 + g * 8);
  }

  f32x4 o[4] = {};
  float mrow[4], lrow[4];
#pragma unroll
  for (int r = 0; r < 4; ++r) { mrow[r] = -3.0e38f; lrow[r] = 0.f; }

  const int srowK = lane >> 3;        // 0..7
  const int vkey  = tid >> 2;         // 0..63
  const int vd3   = tid & 3;          // vd0 = vd3*16

#pragma unroll 1
  for (int kb = 0; kb < SEQ; kb += 64) {
    // ---- pre-sync: issue global reads (no LDS touched) ----
    float mpre[4][4];
#pragma unroll
    for (int r = 0; r < 4; ++r) {
      int q = qt * 64 + w * 16 + g * 4 + r;
      const float* mp = mask + ((size_t)b * SEQ + q) * SEQ + kb;
#pragma unroll
      for (int ni = 0; ni < 4; ++ni) mpre[r][ni] = mp[ni * 16 + r16];
    }
    const u16* vp = qkv + ((tokbase + kb + vkey) * 3 + 2) * HID + h * HD + vd3 * 16;
    u16x8 v0 = *reinterpret_cast<const u16x8*>(vp);
    u16x8 v1 = *reinterpret_cast<const u16x8*>(vp + 8);

    __syncthreads();   // previous iteration's LDS reads done

    // ---- stage K via global_load_lds with pre-swizzled source ----
#pragma unroll
    for (int c = 0; c < 2; ++c) {
      int seg = w * 2 + c;                               // 0..7
      int sK  = ((seg >> 1) + srowK) & 7;                // s(row), row = seg*8+srowK
      int srcc = (lane & 7) ^ sK;
      gld_lds16(qkv + ((tokbase + kb + seg * 8 + srowK) * 3 + 1) * HID + h * HD + srcc * 8,
                &Kt[seg * 512]);
    }
    // ---- stage V transposed, swizzled scalar writes ----
#pragma unroll
    for (int j = 0; j < 16; ++j) {
      u16 val = (j < 8) ? (u16)v0[j] : (u16)v1[j - 8];
      int row = vd3 * 16 + j;                            // d
      int sV  = (vd3 + (j & 7)) & 7;                     // s(row)
      Vt[row * 64 + (((vkey >> 3) ^ sV) << 3) + (vkey & 7)] = val;
    }
    __syncthreads();

    // ---- S = Q K^T (per wave: 16q x 64k) ----
    f32x4 sf[4] = {};
#pragma unroll
    for (int ko = 0; ko < 2; ++ko) {
      bf16x8 bk[4];
#pragma unroll
      for (int ni = 0; ni < 4; ++ni) {
        int row = ni * 16 + r16;
        int sK  = (ni + (r16 & 7)) & 7;
        bk[ni] = *reinterpret_cast<const bf16x8*>(
            &Kt[row * 64 + (((ko * 4 + g) ^ sK) << 3)]);
      }
#pragma unroll
      for (int ni = 0; ni < 4; ++ni)
        sf[ni] = __builtin_amdgcn_mfma_f32_16x16x32_bf16(aq[ko], bk[ni], sf[ni], 0, 0, 0);
    }

    // ---- online softmax (rows at g*4+r, cols at r16) ----
#pragma unroll
    for (int r = 0; r < 4; ++r) {
      float mx = -3.0e38f;
#pragma unroll
      for (int ni = 0; ni < 4; ++ni) {
        float sv = sf[ni][r] * 0.125f + mpre[r][ni];
        sf[ni][r] = sv;
        mx = fmaxf(mx, sv);
      }
      mx = fmaxf(mx, __shfl_xor(mx, 1));
      mx = fmaxf(mx, __shfl_xor(mx, 2));
      mx = fmaxf(mx, __shfl_xor(mx, 4));
      mx = fmaxf(mx, __shfl_xor(mx, 8));
      float mnew  = fmaxf(mrow[r], mx);
      float alpha = __expf(mrow[r] - mnew);
      mrow[r] = mnew;
      float s = 0.f;
#pragma unroll
      for (int ni = 0; ni < 4; ++ni) {
        float p = __expf(sf[ni][r] - mnew);
        sf[ni][r] = p;
        s += p;
      }
      s += __shfl_xor(s, 1); s += __shfl_xor(s, 2);
      s += __shfl_xor(s, 4); s += __shfl_xor(s, 8);
      lrow[r] = lrow[r] * alpha + s;
#pragma unroll
      for (int di = 0; di < 4; ++di) o[di][r] *= alpha;
      // P write: row = g*4+r (s = row&7), col = ni*16+r16
      int prow = g * 4 + r;
      int sP   = prow & 7;
#pragma unroll
      for (int ni = 0; ni < 4; ++ni) {
        int chunk = ni * 2 + (r16 >> 3);
        Pl[w][prow * 64 + ((chunk ^ sP) << 3) + (r16 & 7)] = f2bf(sf[ni][r]);
      }
    }
    __syncthreads();   // P visible (cross-lane)

    // ---- O += P V ----
#pragma unroll
    for (int kk = 0; kk < 2; ++kk) {
      bf16x8 pa, bv[4];
      pa = *reinterpret_cast<const bf16x8*>(
          &Pl[w][r16 * 64 + (((kk * 4 + g) ^ (r16 & 7)) << 3)]);
#pragma unroll
      for (int di = 0; di < 4; ++di) {
        int row = di * 16 + r16;
        int sV  = (di + (r16 & 7)) & 7;
        bv[di] = *reinterpret_cast<const bf16x8*>(
            &Vt[row * 64 + (((kk * 4 + g) ^ sV) << 3)]);
      }
#pragma unroll
      for (int di = 0; di < 4; ++di)
        o[di] = __builtin_amdgcn_mfma_f32_16x16x32_bf16(pa, bv[di], o[di], 0, 0, 0);
    }
  }

  // finalize
#pragma unroll
  for (int di = 0; di < 4; ++di)
#pragma unroll
    for (int r = 0; r < 4; ++r) {
      int srow = qt * 64 + w * 16 + g * 4 + r;
      float val = o[di][r] / lrow[r];
      AO[(tokbase + srow) * HID + h * HD + di * 16 + r16] = f2bf(val);
    }
}

// ---------------- launcher ----------------
extern "C" void kernel_launch(void* const* d_in, const int* in_sizes, int n_in,
                              void* d_out, int out_size, void* d_ws, size_t ws_size,
                              hipStream_t stream) {
  (void)in_sizes; (void)n_in; (void)out_size; (void)ws_size;
  const float* hs   = (const float*)d_in[0];
  const float* mask = (const float*)d_in[1];
  const float* wqkv = (const float*)d_in[2];
  const float* wo   = (const float*)d_in[3];
  float* out = (float*)d_out;

  char* ws   = (char*)d_ws;
  u16* Xb    = (u16*)(ws);                        // 4096x1024  (8 MiB)
  u16* Wqkvb = (u16*)(ws + 8u  * 1024 * 1024);    // 3072x1024  (6 MiB)
  u16* Wob   = (u16*)(ws + 14u * 1024 * 1024);    // 1024x1024  (2 MiB)
  u16* QKVb  = (u16*)(ws + 16u * 1024 * 1024);    // 4096x3072  (24 MiB)
  u16* AOb   = (u16*)(ws + 40u * 1024 * 1024);    // 4096x1024  (8 MiB)

  cvt_kernel<<<4096, 256, 0, stream>>>(hs,   Xb);
  cvt_kernel<<<3072, 256, 0, stream>>>(wqkv, Wqkvb);
  cvt_kernel<<<1024, 256, 0, stream>>>(wo,   Wob);

  gemm_bt<true ><<<dim3(3072 / 128, 4096 / 128), 256, 0, stream>>>(Xb,  Wqkvb, QKVb, NTOK, 3072, HID);
  attn_kernel   <<<1024, 256, 0, stream>>>(QKVb, mask, AOb);
  gemm_bt<false><<<dim3(1024 / 128, 4096 / 128), 256, 0, stream>>>(AOb, Wob,  out,  NTOK, 1024, HID);
}